// Round 13
// baseline (845.305 us; speedup 1.0000x reference)
//
#include <hip/hip_runtime.h>
#include <hip/hip_bf16.h>
#include <stdint.h>

// ConvIntrinsic: fused  out[k,o,t] = relu( Σ_f sw[t,f]·ms[k,f]
//                + Σ_{x,y,f} W3[o,t,x,y,f]·interp0[k,x,y,f] + bias[t] )
// => GEMM (K=100000 × 1312) @ (1312 × 768), o=8 column duplicates o=0.
//
// R12: R10-verbatim two-kernel split; gemm_main BM 64->32 ONLY (minimal
// delta after R11's unexplained inf). 8 waves, wave tile 32x96 ->
// acc[2][6]=48 acc regs, ~122 total, __launch_bounds__(512,4) -> 4
// waves/SIMD, 2 blocks/CU (vs R10's 2 waves/SIMD at 96 acc regs).
// A addressing: per-thread base + c*64 immediate (fits 13-bit signed).
// Grid 3125*32 = 100000 exact. Ap-in-out aliasing still race-free
// (blocks read only their own 32 rows, then overwrite them).

typedef __attribute__((ext_vector_type(8))) short short8;
typedef __attribute__((ext_vector_type(4))) float floatx4;
typedef __attribute__((ext_vector_type(2))) float fx2;

#define KPTS 100000
#define OUT_STRIDE 864        // floats per k-row (9*96)
#define ROW_BYTES 3456        // OUT_STRIDE*4
#define BP_SHORTS 1007616     // 41*48*64*8

__device__ __forceinline__ short f2bf(float x) {
  union { float f; uint32_t u; } c; c.f = x;
  uint32_t u = c.u;
  u += 0x7FFFu + ((u >> 16) & 1u);   // round-to-nearest-even
  return (short)(u >> 16);
}
__device__ __forceinline__ float bf2f(short s) {
  union { uint32_t u; float f; } c;
  c.u = ((uint32_t)(uint16_t)s) << 16;
  return c.f;
}

// ---------------- prep: ms -> bf16 table --------------------------------
__global__ void prep_ms(const float* __restrict__ ms, short* __restrict__ msb) {
  const int i = (blockIdx.x * 256 + threadIdx.x) * 8;
  if (i < KPTS * 32) {
    floatx4 a = *(const floatx4*)(ms + i);
    floatx4 b = *(const floatx4*)(ms + i + 4);
    short8 s;
#pragma unroll
    for (int j = 0; j < 4; ++j) { s[j] = f2bf(a[j]); s[4 + j] = f2bf(b[j]); }
    *reinterpret_cast<short8*>(msb + i) = s;
  }
}

// ---------------- prep: pack B in MFMA fragment layout --------------------
// Bp[ch][ntile][lane][j] = B[c = ch*32 + (lane>>4)*8 + j][n = ntile*16 + (lane&15)]
__global__ void prep_B(const float* __restrict__ kern,
                       const float* __restrict__ tw,
                       const float* __restrict__ sw,
                       short* __restrict__ Bp) {
  const int ntile = blockIdx.x;   // 0..47
  const int ch    = blockIdx.y;   // 0..40
  const int lane  = threadIdx.x;  // 0..63
  const int n = ntile * 16 + (lane & 15);
  const int o = n / 96;
  const int t = n - o * 96;
  const int fb = (lane >> 4) * 8;

  short8 v;
  if (ch < 40) {
    float kcol[40];
#pragma unroll
    for (int ra = 0; ra < 40; ++ra) kcol[ra] = kern[ra * 40 + ch];
#pragma unroll
    for (int j = 0; j < 8; ++j) {
      const int f = fb + j;
      float acc = 0.f;
      for (int r = 0; r < 5; ++r) {
#pragma unroll
        for (int a = 0; a < 8; ++a) {
          acc += kcol[r * 8 + a] * tw[((t * 5 + r) * 8 + ((a + o) & 7)) * 32 + f];
        }
      }
      v[j] = f2bf(acc);
    }
  } else {
#pragma unroll
    for (int j = 0; j < 8; ++j) v[j] = f2bf(sw[t * 32 + fb + j]);
  }
  *reinterpret_cast<short8*>(Bp + ((size_t)(ch * 48 + ntile) * 64 + lane) * 8) = v;
}

// ---------------- interp: build A in fragment layout ----------------------
// wave w = (ktile, ch); lane l handles row = ktile*16 + (l&15),
// f-block fb = (l>>4)*8. Writes 16 B to Ap[k-row] inside d_out.
__global__ __launch_bounds__(256, 8) void interp_A(
    const short* __restrict__ msb,
    const float* __restrict__ bary,
    char* __restrict__ apb) {
  const int w = blockIdx.x * 4 + (threadIdx.x >> 6);
  if (w >= 6250 * 41) return;
  const int lane = threadIdx.x & 63;
  const int ktile = w / 41;
  const int ch = w - ktile * 41;
  const int row = ktile * 16 + (lane & 15);
  const int fb = (lane >> 4) * 8;

  short8 v;
  if (ch == 40) {                      // center chunk: pass-through
    v = *(const short8*)(msb + (size_t)row * 32 + fb);
  } else {
    const float* bp = bary + (size_t)row * 240 + ch * 6;
    fx2 p0 = __builtin_nontemporal_load((const fx2*)bp);
    fx2 p1 = __builtin_nontemporal_load((const fx2*)(bp + 2));
    fx2 p2 = __builtin_nontemporal_load((const fx2*)(bp + 4));
    short8 A = *(const short8*)(msb + ((size_t)(int)p0.x) * 32 + fb);
    short8 B = *(const short8*)(msb + ((size_t)(int)p1.x) * 32 + fb);
    short8 C = *(const short8*)(msb + ((size_t)(int)p2.x) * 32 + fb);
#pragma unroll
    for (int j = 0; j < 8; ++j)
      v[j] = f2bf(p0.y * bf2f(A[j]) + p1.y * bf2f(B[j]) + p2.y * bf2f(C[j]));
  }
  *reinterpret_cast<short8*>(apb + (size_t)row * ROW_BYTES + ch * 64 + (lane >> 4) * 16) = v;
}

// ---------------- barrier-free GEMM (BM=32, 8 waves, wave tile 32x96) -----
__global__ __launch_bounds__(512, 4) void gemm_main(
    const char* __restrict__ apb,
    const short* __restrict__ Bp,
    const float* __restrict__ bias,
    float* __restrict__ out) {
  const int kbase = blockIdx.x * 32;
  const int tid = threadIdx.x;
  const int lane = tid & 63;
  const int wn = tid >> 6;             // 0..7 (cols wn*96)
  const int l15 = lane & 15;
  const int kh = lane >> 4;            // 0..3

  // clamped A rows (grid is exact: clamp only a formality)
  int rowm[2];
#pragma unroll
  for (int mi = 0; mi < 2; ++mi) {
    int r = kbase + mi * 16 + l15;
    rowm[mi] = (r < KPTS) ? r : (KPTS - 1);
  }

  auto loadA = [&](int c, short8* dst) {
#pragma unroll
    for (int mi = 0; mi < 2; ++mi)
      dst[mi] = *reinterpret_cast<const short8*>(
          apb + (size_t)rowm[mi] * ROW_BYTES + c * 64 + kh * 16);
  };
  auto loadB = [&](int c, short8* dst) {
    const short* bp = Bp + ((size_t)(c * 48 + wn * 6) * 64 + lane) * 8;
#pragma unroll
    for (int j = 0; j < 6; ++j)
      dst[j] = *reinterpret_cast<const short8*>(bp + (size_t)j * 512);
  };

  floatx4 acc[2][6];
#pragma unroll
  for (int mi = 0; mi < 2; ++mi)
#pragma unroll
    for (int nj = 0; nj < 6; ++nj) acc[mi][nj] = (floatx4)0.f;

  short8 af[2], bf[6], naf[2], nbf[6];
  loadA(0, af);
  loadB(0, bf);

  for (int ch = 0; ch < 41; ++ch) {
    if (ch < 40) { loadA(ch + 1, naf); loadB(ch + 1, nbf); }
#pragma unroll
    for (int nj = 0; nj < 6; ++nj)
#pragma unroll
      for (int mi = 0; mi < 2; ++mi)
        acc[mi][nj] = __builtin_amdgcn_mfma_f32_16x16x32_bf16(af[mi], bf[nj],
                                                              acc[mi][nj], 0, 0, 0);
#pragma unroll
    for (int mi = 0; mi < 2; ++mi) af[mi] = naf[mi];
#pragma unroll
    for (int nj = 0; nj < 6; ++nj) bf[nj] = nbf[nj];
  }

  // epilogue: bias + relu; out[k,o,t] = out[k*864 + n]; o=8 duplicates o=0
#pragma unroll
  for (int mi = 0; mi < 2; ++mi) {
    const int rb = kbase + mi * 16 + kh * 4;
#pragma unroll
    for (int nj = 0; nj < 6; ++nj) {
      const int n = wn * 96 + nj * 16 + l15;
      const float bsv = bias[nj * 16 + l15];
      const bool dup = (wn == 0);
#pragma unroll
      for (int i = 0; i < 4; ++i) {
        const int r = rb + i;
        if (r < KPTS) {
          float vv = fmaxf(acc[mi][nj][i] + bsv, 0.f);
          out[(size_t)r * OUT_STRIDE + n] = vv;
          if (dup) out[(size_t)r * OUT_STRIDE + 768 + n] = vv;
        }
      }
    }
  }
}

extern "C" void kernel_launch(void* const* d_in, const int* in_sizes, int n_in,
                              void* d_out, int out_size, void* d_ws, size_t ws_size,
                              hipStream_t stream) {
  const float* ms   = (const float*)d_in[0];  // (K,32)
  const float* bary = (const float*)d_in[1];  // (K,5,8,3,2)
  const float* kern = (const float*)d_in[2];  // (5,8,5,8)
  const float* tw   = (const float*)d_in[3];  // (96,5,8,32)
  const float* sw   = (const float*)d_in[4];  // (96,1,32)
  const float* bias = (const float*)d_in[5];  // (96,)
  float* out = (float*)d_out;
  short* Bp  = (short*)d_ws;                  // 2.02 MB
  short* msb = (short*)d_ws + BP_SHORTS;      // bf16 ms table, 6.4 MB
  char* apb  = (char*)d_out;                  // Ap[k] ⊂ out-region[k]

  hipLaunchKernelGGL(prep_B, dim3(48, 41), dim3(64), 0, stream, kern, tw, sw, Bp);
  hipLaunchKernelGGL(prep_ms, dim3((KPTS * 32 / 8 + 255) / 256), dim3(256), 0, stream,
                     ms, msb);
  hipLaunchKernelGGL(interp_A, dim3((6250 * 41 + 3) / 4), dim3(256), 0, stream,
                     msb, bary, apb);
  hipLaunchKernelGGL(gemm_main, dim3(3125), dim3(512), 0, stream,
                     apb, Bp, bias, out);
}

// Round 14
// 598.178 us; speedup vs baseline: 1.4131x; 1.4131x over previous
//
#include <hip/hip_runtime.h>
#include <hip/hip_bf16.h>
#include <stdint.h>

// ConvIntrinsic: fused  out[k,o,t] = relu( Σ_f sw[t,f]·ms[k,f]
//                + Σ_{x,y,f} W3[o,t,x,y,f]·interp0[k,x,y,f] + bias[t] )
// => GEMM (K=100000 × 1312) @ (1312 × 768), o=8 column duplicates o=0.
//
// R13: fused kernel, 16 waves / 1024 threads, wave tile 64x48 (acc[4][3]
// = 48 regs) -> ~110 total regs -> __launch_bounds__(1024,4) = 4 waves/SIMD
// at UNCHANGED per-CU traffic (BM=64, BN=768: full B per block = 48KB/CU/
// chunk, gathers built once). This is the unexplored cell: R6/R12 raised
// occupancy but multiplied VMEM per CU; R7 kept traffic minimal at 2
// waves/SIMD. Builders = tid<256 (R8 4-thr/row bf16 path); 1-ahead gather
// pipeline (R1-proven ordering); single bf[3] B-set; R7 barrier form.

typedef __attribute__((ext_vector_type(8))) short short8;
typedef __attribute__((ext_vector_type(4))) float floatx4;
typedef __attribute__((ext_vector_type(2))) float fx2;

#define KPTS 100000
#define OUT_STRIDE 864        // floats per k-row (9*96)
#define BM 64
#define BP_SHORTS 1007616     // 41*48*64*8

// Workgroup barrier without vmcnt drain (R7 form).
#define BARRIER() do {                              \
    __builtin_amdgcn_sched_barrier(0);              \
    asm volatile("s_waitcnt lgkmcnt(0)");           \
    __builtin_amdgcn_s_barrier();                   \
  } while (0)

__device__ __forceinline__ short f2bf(float x) {
  union { float f; uint32_t u; } c; c.f = x;
  uint32_t u = c.u;
  u += 0x7FFFu + ((u >> 16) & 1u);   // round-to-nearest-even
  return (short)(u >> 16);
}
__device__ __forceinline__ float bf2f(short s) {
  union { uint32_t u; float f; } c;
  c.u = ((uint32_t)(uint16_t)s) << 16;
  return c.f;
}

// ---------------- prep: ms -> bf16 table --------------------------------
__global__ void prep_ms(const float* __restrict__ ms, short* __restrict__ msb) {
  const int i = (blockIdx.x * 256 + threadIdx.x) * 8;
  if (i < KPTS * 32) {
    floatx4 a = *(const floatx4*)(ms + i);
    floatx4 b = *(const floatx4*)(ms + i + 4);
    short8 s;
#pragma unroll
    for (int j = 0; j < 4; ++j) { s[j] = f2bf(a[j]); s[4 + j] = f2bf(b[j]); }
    *reinterpret_cast<short8*>(msb + i) = s;
  }
}

// ---------------- prep: pack B in MFMA fragment layout --------------------
// Bp[ch][ntile][lane][j] = B[c = ch*32 + (lane>>4)*8 + j][n = ntile*16 + (lane&15)]
__global__ void prep_B(const float* __restrict__ kern,
                       const float* __restrict__ tw,
                       const float* __restrict__ sw,
                       short* __restrict__ Bp) {
  const int ntile = blockIdx.x;   // 0..47
  const int ch    = blockIdx.y;   // 0..40
  const int lane  = threadIdx.x;  // 0..63
  const int n = ntile * 16 + (lane & 15);
  const int o = n / 96;
  const int t = n - o * 96;
  const int fb = (lane >> 4) * 8;

  short8 v;
  if (ch < 40) {
    float kcol[40];
#pragma unroll
    for (int ra = 0; ra < 40; ++ra) kcol[ra] = kern[ra * 40 + ch];
#pragma unroll
    for (int j = 0; j < 8; ++j) {
      const int f = fb + j;
      float acc = 0.f;
      for (int r = 0; r < 5; ++r) {
#pragma unroll
        for (int a = 0; a < 8; ++a) {
          acc += kcol[r * 8 + a] * tw[((t * 5 + r) * 8 + ((a + o) & 7)) * 32 + f];
        }
      }
      v[j] = f2bf(acc);
    }
  } else {
#pragma unroll
    for (int j = 0; j < 8; ++j) v[j] = f2bf(sw[t * 32 + fb + j]);
  }
  *reinterpret_cast<short8*>(Bp + ((size_t)(ch * 48 + ntile) * 64 + lane) * 8) = v;
}

// ---------------- main fused GEMM (16 waves, wave tile 64x48) -------------
__global__ __launch_bounds__(1024, 4) void conv_main(
    const short* __restrict__ msb,
    const float* __restrict__ bary,
    const float* __restrict__ bias,
    const short* __restrict__ Bp,
    float* __restrict__ out) {
  __shared__ short Atile[2][BM][40];   // 32 used cols + 8 pad shorts

  const int kbase = blockIdx.x * BM;
  const int tid = threadIdx.x;
  const int lane = tid & 63;
  const int wid = tid >> 6;            // 0..15 (cols wid*48)
  const int l15 = lane & 15;
  const int kh = lane >> 4;            // 0..3

  // A-build role: 4 threads per row, 8 bf16 f-columns each; 256 builders
  // (waves 0-3). Waves 4-15 are pure-MFMA.
  const bool builder = tid < 256;
  const int arow = tid >> 2;           // 0..63 for builders
  const int af0 = (tid & 3) * 8;       // 0,8,16,24
  const int krow = kbase + (arow & 63);
  const bool rowok = builder && (krow < KPTS);
  const float* __restrict__ brow = bary + (size_t)(rowok ? krow : 0) * 240;
  const short* __restrict__ mrowb = msb + (size_t)(rowok ? krow : 0) * 32 + af0;

  fx2 q0, q1, q2;                      // bary for next chunk (1 ahead)
  short8 G0, G1, G2;                   // gathers in flight (issue top, commit bottom)
  float W0, W1, W2;

  auto ldbary = [&](int c) {
    if (rowok) {
      const fx2* bp = (const fx2*)(brow + c * 6);
      q0 = __builtin_nontemporal_load(bp);
      q1 = __builtin_nontemporal_load(bp + 1);
      q2 = __builtin_nontemporal_load(bp + 2);
    } else {
      q0 = (fx2)0.f; q1 = (fx2)0.f; q2 = (fx2)0.f;
    }
  };
  auto issueG = [&](int c) {
    if (c == 40) {                     // center chunk: pass-through
      G0 = *(const short8*)(mrowb);
      G1 = G0; G2 = G0;
      W0 = rowok ? 1.f : 0.f; W1 = 0.f; W2 = 0.f;
    } else {
      G0 = *(const short8*)(msb + ((size_t)(int)q0.x) * 32 + af0);
      G1 = *(const short8*)(msb + ((size_t)(int)q1.x) * 32 + af0);
      G2 = *(const short8*)(msb + ((size_t)(int)q2.x) * 32 + af0);
      W0 = q0.y; W1 = q1.y; W2 = q2.y;
    }
  };
  auto commitG = [&](int buf) {
    short8 s;
#pragma unroll
    for (int j = 0; j < 8; ++j)
      s[j] = f2bf(W0 * bf2f(G0[j]) + W1 * bf2f(G1[j]) + W2 * bf2f(G2[j]));
    *reinterpret_cast<short8*>(&Atile[buf][arow][af0]) = s;
  };

  short8 bf[3];
  auto loadB = [&](int c) {
    const short* bp = Bp + ((size_t)(c * 48 + wid * 3) * 64 + lane) * 8;
#pragma unroll
    for (int j = 0; j < 3; ++j)
      bf[j] = *reinterpret_cast<const short8*>(bp + (size_t)j * 512);
  };

  floatx4 acc[4][3];
#pragma unroll
  for (int mi = 0; mi < 4; ++mi)
#pragma unroll
    for (int nj = 0; nj < 3; ++nj) acc[mi][nj] = (floatx4)0.f;

  // ---- prologue: build chunk 0 (one exposed stall, once) ----
  if (builder) {
    ldbary(0);
    issueG(0);
    commitG(0);
    ldbary(1);                         // q = bary(1) for window 0
  }
  BARRIER();

  for (int ch = 0; ch <= 40; ++ch) {
    const int cur = ch & 1;
    if (builder) {
      if (ch < 40) issueG(ch + 1);     // gathers -> regs (addresses from q)
      if (ch + 2 <= 39) ldbary(ch + 2);
    }
    loadB(ch);

    short8 af[4];
#pragma unroll
    for (int mi = 0; mi < 4; ++mi)
      af[mi] = *reinterpret_cast<const short8*>(&Atile[cur][mi * 16 + l15][kh * 8]);
#pragma unroll
    for (int nj = 0; nj < 3; ++nj)
#pragma unroll
      for (int mi = 0; mi < 4; ++mi)
        acc[mi][nj] = __builtin_amdgcn_mfma_f32_16x16x32_bf16(af[mi], bf[nj],
                                                              acc[mi][nj], 0, 0, 0);

    if (builder && ch < 40) commitG(cur ^ 1);  // interp + ds_write next buf
    BARRIER();
  }

  // epilogue: bias + relu; out[k,o,t] = out[k*864 + n]; o=8 duplicates o=0
#pragma unroll
  for (int mi = 0; mi < 4; ++mi) {
    const int rb = kbase + mi * 16 + kh * 4;
#pragma unroll
    for (int nj = 0; nj < 3; ++nj) {
      const int n = wid * 48 + nj * 16 + l15;
      const float bsv = bias[(wid & 1) * 48 + nj * 16 + l15];   // = bias[n % 96]
      const bool dup = (n < 96);
#pragma unroll
      for (int i = 0; i < 4; ++i) {
        const int r = rb + i;
        if (r < KPTS) {
          float vv = fmaxf(acc[mi][nj][i] + bsv, 0.f);
          out[(size_t)r * OUT_STRIDE + n] = vv;
          if (dup) out[(size_t)r * OUT_STRIDE + 768 + n] = vv;
        }
      }
    }
  }
}

extern "C" void kernel_launch(void* const* d_in, const int* in_sizes, int n_in,
                              void* d_out, int out_size, void* d_ws, size_t ws_size,
                              hipStream_t stream) {
  const float* ms   = (const float*)d_in[0];  // (K,32)
  const float* bary = (const float*)d_in[1];  // (K,5,8,3,2)
  const float* kern = (const float*)d_in[2];  // (5,8,5,8)
  const float* tw   = (const float*)d_in[3];  // (96,5,8,32)
  const float* sw   = (const float*)d_in[4];  // (96,1,32)
  const float* bias = (const float*)d_in[5];  // (96,)
  float* out = (float*)d_out;
  short* Bp  = (short*)d_ws;                  // 2.02 MB
  short* msb = (short*)d_ws + BP_SHORTS;      // bf16 ms table, 6.4 MB

  hipLaunchKernelGGL(prep_B, dim3(48, 41), dim3(64), 0, stream, kern, tw, sw, Bp);
  hipLaunchKernelGGL(prep_ms, dim3((KPTS * 32 / 8 + 255) / 256), dim3(256), 0, stream,
                     ms, msb);
  hipLaunchKernelGGL(conv_main, dim3(1563), dim3(1024), 0, stream,
                     msb, bary, bias, Bp, out);
}